// Round 3
// 675.624 us; speedup vs baseline: 1.0208x; 1.0208x over previous
//
#include <hip/hip_runtime.h>
#include <hip/hip_bf16.h>
#include <stdint.h>

#define NSEQ 900
#define CH 256
#define NH 8
#define HD 32
#define SCALE 0.17677669529663687f  // 32^-0.5
#define VTP 912                     // padded Vt row length (16B-aligned rows)

typedef unsigned short u16;
typedef __attribute__((ext_vector_type(8))) short bf16x8;
typedef __attribute__((ext_vector_type(4))) float f32x4;

__device__ __forceinline__ uint32_t f2bf(float f) {  // fp32 -> bf16 bits, RNE
  uint32_t u = __float_as_uint(f);
  return (u + 0x7fffu + ((u >> 16) & 1u)) >> 16;
}

__device__ __forceinline__ uint32_t pkbf2(float a, float b) {  // v_cvt_pk_bf16_f32
  __hip_bfloat162 h = __float22bfloat162_rn(make_float2(a, b));
  uint32_t u;
  __builtin_memcpy(&u, &h, 4);
  return u;
}

__device__ __forceinline__ uint4 pack8(float4 a, float4 b) {
  uint4 r;
  r.x = f2bf(a.x) | (f2bf(a.y) << 16);
  r.y = f2bf(a.z) | (f2bf(a.w) << 16);
  r.z = f2bf(b.x) | (f2bf(b.y) << 16);
  r.w = f2bf(b.z) | (f2bf(b.w) << 16);
  return r;
}

// ---------------- kernel 1: QKV projections (bf16 MFMA, 64x64 tile) ----------
// out = X @ W^T + bias; X [14400][256] fp32 (row = n*16+b), W [256][256] fp32.
// Epilogue: LDS-staged tile, 256B-coalesced uint4 stores into bf16 [B,H,N,D].
__global__ __launch_bounds__(256) void proj_qkv_kernel(
    const float* __restrict__ xq, const float* __restrict__ xk, const float* __restrict__ xv,
    const float* __restrict__ Wq, const float* __restrict__ Wk, const float* __restrict__ Wv,
    const float* __restrict__ bq, const float* __restrict__ bk, const float* __restrict__ bv,
    u16* __restrict__ Q, u16* __restrict__ K, u16* __restrict__ V) {
  __shared__ u16 smem[5120];  // K-loop: As(2560)+Bs(2560); epilogue: 64x72 tile
  const int t = threadIdx.x;
  const int r0 = blockIdx.x * 64, c0 = blockIdx.y * 64;
  const int mode = blockIdx.z;
  const float* X    = (mode == 0) ? xq : (mode == 1) ? xk : xv;
  const float* W    = (mode == 0) ? Wq : (mode == 1) ? Wk : Wv;
  const float* bias = (mode == 0) ? bq : (mode == 1) ? bk : bv;
  u16* OUT          = (mode == 0) ? Q  : (mode == 1) ? K  : V;

  const int lane = t & 63, wv = t >> 6;
  const int wr = (wv >> 1) * 32, wc = (wv & 1) * 32;
  const int lr = lane & 15, lq = lane >> 4;
  const int arow = t >> 2, akq = (t & 3) * 8;
  const float* Xr = X + (r0 + arow) * CH + akq;
  const float* Wr = W + (c0 + arow) * CH + akq;

  f32x4 acc[2][2];
#pragma unroll
  for (int i = 0; i < 2; ++i)
#pragma unroll
    for (int j = 0; j < 2; ++j) acc[i][j] = (f32x4){0.f, 0.f, 0.f, 0.f};

  for (int kc = 0; kc < CH; kc += 32) {
    const float4 a0 = *(const float4*)(Xr + kc);
    const float4 a1 = *(const float4*)(Xr + kc + 4);
    const float4 b0 = *(const float4*)(Wr + kc);
    const float4 b1 = *(const float4*)(Wr + kc + 4);
    __syncthreads();
    *(uint4*)&smem[arow * 40 + akq]        = pack8(a0, a1);
    *(uint4*)&smem[2560 + arow * 40 + akq] = pack8(b0, b1);
    __syncthreads();
    const bf16x8 af0 = *(const bf16x8*)&smem[(wr + lr) * 40 + lq * 8];
    const bf16x8 af1 = *(const bf16x8*)&smem[(wr + 16 + lr) * 40 + lq * 8];
    const bf16x8 bf0 = *(const bf16x8*)&smem[2560 + (wc + lr) * 40 + lq * 8];
    const bf16x8 bf1 = *(const bf16x8*)&smem[2560 + (wc + 16 + lr) * 40 + lq * 8];
    acc[0][0] = __builtin_amdgcn_mfma_f32_16x16x32_bf16(af0, bf0, acc[0][0], 0, 0, 0);
    acc[0][1] = __builtin_amdgcn_mfma_f32_16x16x32_bf16(af0, bf1, acc[0][1], 0, 0, 0);
    acc[1][0] = __builtin_amdgcn_mfma_f32_16x16x32_bf16(af1, bf0, acc[1][0], 0, 0, 0);
    acc[1][1] = __builtin_amdgcn_mfma_f32_16x16x32_bf16(af1, bf1, acc[1][1], 0, 0, 0);
  }

  // stage tile into LDS (stride 72 u16), C layout: row=(lane>>4)*4+r, col=lane&15
  __syncthreads();
  const float qs = (mode == 0) ? SCALE : 1.0f;
#pragma unroll
  for (int tr = 0; tr < 2; ++tr)
#pragma unroll
    for (int tc = 0; tc < 2; ++tc) {
      const int col = wc + tc * 16 + lr;
      const float bi = bias[c0 + col];
#pragma unroll
      for (int r = 0; r < 4; ++r) {
        const int row = wr + tr * 16 + lq * 4 + r;
        smem[row * 72 + col] = (u16)f2bf((acc[tr][tc][r] + bi) * qs);
      }
    }
  __syncthreads();

  // coalesced store: task = ((b*2+h_l)*4 + nl)*4 + d16 -> 256B contiguous per 16 lanes
  const int n_base = r0 >> 4, h_base = c0 >> 5;
#pragma unroll
  for (int rep = 0; rep < 2; ++rep) {
    const int task = rep * 256 + t;
    const int d16 = task & 3, nl = (task >> 2) & 3, bhl = task >> 4;
    const int hl = bhl & 1, bb = bhl >> 1;
    const int lrow = nl * 16 + bb, lcol = hl * 32 + d16 * 8;
    const uint4 val = *(const uint4*)&smem[lrow * 72 + lcol];
    const size_t o = ((size_t)(bb * NH + h_base + hl) * NSEQ + n_base + nl) * HD + d16 * 8;
    *(uint4*)&OUT[o] = val;
  }
}

// ---------------- kernel 2: V [B,H,N,D] -> Vt [B,H,D,VTP] ----------------
__global__ __launch_bounds__(256) void transpose_v_kernel(
    const u16* __restrict__ V, u16* __restrict__ Vt) {
  __shared__ u16 T[32][136];
  const int t = threadIdx.x;
  const int bh = blockIdx.y;
  const int n0 = blockIdx.x * 128;
  {
    const int i = t >> 1, dh = (t & 1) * 16;
    const int n = min(n0 + i, NSEQ - 1);
    const uint4 v0 = *(const uint4*)&V[((size_t)bh * NSEQ + n) * HD + dh];
    const uint4 v1 = *(const uint4*)&V[((size_t)bh * NSEQ + n) * HD + dh + 8];
    const u16* u = (const u16*)&v0;
#pragma unroll
    for (int j = 0; j < 8; ++j) T[dh + j][i] = u[j];
    const u16* u2 = (const u16*)&v1;
#pragma unroll
    for (int j = 0; j < 8; ++j) T[dh + 8 + j][i] = u2[j];
  }
  __syncthreads();
  const int d = t >> 3, nb = (t & 7) * 16;
  u16* dst = Vt + ((size_t)bh * HD + d) * VTP + n0 + nb;
  if (n0 + nb + 15 < NSEQ) {
    *(uint4*)dst       = *(const uint4*)&T[d][nb];
    *(uint4*)(dst + 8) = *(const uint4*)&T[d][nb + 8];
  } else {
#pragma unroll
    for (int j = 0; j < 16; ++j) {
      const int col = n0 + nb + j;
      if (col < VTP) dst[j] = (col < NSEQ) ? T[d][nb + j] : (u16)0;  // zero pad cols
    }
  }
}

// ---------------- kernel 3: fused attention (MFMA, max-free softmax) --------
// Swapped QK^T: s = mfma(K,Q) puts S[n=n0+lr][m=m0+lq*4+r] in each lane ->
// per-lane FIXED n-row. prior becomes 2x float4 loads, P-pack 2x ds_write_b64,
// denominator a single per-lane accumulator. Ragged tail (cols 896..899) is
// handled outside the loop so the main loop has zero masks/clamps.
__global__ __launch_bounds__(256) void attn_kernel(
    const u16* __restrict__ Q, const u16* __restrict__ K,
    const u16* __restrict__ Vt, const float* __restrict__ prior,
    u16* __restrict__ AO) {
  __shared__ u16 Plds[4][640];       // per-wave 16x32 P tile, 40-u16 row stride
  __shared__ float Ow[4][16][32];
  __shared__ float Lw[4][16];

  const int t = threadIdx.x;
  const int n0 = blockIdx.x * 16;
  const int bh = blockIdx.y;
  const int lane = t & 63, wv = t >> 6;
  const int lr = lane & 15, lq = lane >> 4;

  const u16* Qb = Q + (size_t)bh * NSEQ * HD;
  const u16* Kb = K + (size_t)bh * NSEQ * HD;
  const u16* Vb = Vt + (size_t)bh * HD * VTP;
  const float* Pb = prior + (size_t)bh * NSEQ * NSEQ;

  const int qrow = min(n0 + lr, NSEQ - 1);
  const bf16x8 qf = *(const bf16x8*)&Qb[qrow * HD + lq * 8];
  const float* Prow = Pb + (size_t)qrow * NSEQ;  // this lane's prior row (n)

  f32x4 acc0 = {0.f, 0.f, 0.f, 0.f};
  f32x4 acc1 = {0.f, 0.f, 0.f, 0.f};
  float lsum = 0.f;
  u16* Pw = &Plds[wv][0];

  for (int c = wv; c < 28; c += 4) {  // 28 full chunks of 32 = cols 0..895
    const int m0 = c * 32;
    const bf16x8 kf0 = *(const bf16x8*)&Kb[(m0 + lr) * HD + lq * 8];
    const bf16x8 kf1 = *(const bf16x8*)&Kb[(m0 + 16 + lr) * HD + lq * 8];
    const float4 pA = *(const float4*)&Prow[m0 + lq * 4];
    const float4 pB = *(const float4*)&Prow[m0 + 16 + lq * 4];
    const f32x4 z = {0.f, 0.f, 0.f, 0.f};
    const f32x4 s0 = __builtin_amdgcn_mfma_f32_16x16x32_bf16(kf0, qf, z, 0, 0, 0);
    const f32x4 s1 = __builtin_amdgcn_mfma_f32_16x16x32_bf16(kf1, qf, z, 0, 0, 0);
    const float e0 = __expf(s0[0] * pA.x), e1 = __expf(s0[1] * pA.y);
    const float e2 = __expf(s0[2] * pA.z), e3 = __expf(s0[3] * pA.w);
    const float e4 = __expf(s1[0] * pB.x), e5 = __expf(s1[1] * pB.y);
    const float e6 = __expf(s1[2] * pB.z), e7 = __expf(s1[3] * pB.w);
    lsum += ((e0 + e1) + (e2 + e3)) + ((e4 + e5) + (e6 + e7));
    uint2 w0, w1;
    w0.x = pkbf2(e0, e1); w0.y = pkbf2(e2, e3);
    w1.x = pkbf2(e4, e5); w1.y = pkbf2(e6, e7);
    *(uint2*)&Pw[lr * 40 + lq * 4]      = w0;
    *(uint2*)&Pw[lr * 40 + 16 + lq * 4] = w1;
    const bf16x8 pf  = *(const bf16x8*)&Pw[lr * 40 + lq * 8];
    const bf16x8 vf0 = *(const bf16x8*)&Vb[lr * VTP + m0 + lq * 8];
    const bf16x8 vf1 = *(const bf16x8*)&Vb[(16 + lr) * VTP + m0 + lq * 8];
    acc0 = __builtin_amdgcn_mfma_f32_16x16x32_bf16(pf, vf0, acc0, 0, 0, 0);
    acc1 = __builtin_amdgcn_mfma_f32_16x16x32_bf16(pf, vf1, acc1, 0, 0, 0);
  }

  if (wv == 0) {  // tail chunk: cols 896..899 valid (4 of 32)
    const int m0 = 896;
    const bf16x8 kf0 = *(const bf16x8*)&Kb[min(m0 + lr, NSEQ - 1) * HD + lq * 8];
    const float4 pA = *(const float4*)&Prow[m0];  // cols 896..899
    const f32x4 z = {0.f, 0.f, 0.f, 0.f};
    const f32x4 s0 = __builtin_amdgcn_mfma_f32_16x16x32_bf16(kf0, qf, z, 0, 0, 0);
    float e0 = 0.f, e1 = 0.f, e2 = 0.f, e3 = 0.f;
    if (lq == 0) {  // only C-rows 0..3 (m=896..899) are valid
      e0 = __expf(s0[0] * pA.x); e1 = __expf(s0[1] * pA.y);
      e2 = __expf(s0[2] * pA.z); e3 = __expf(s0[3] * pA.w);
    }
    lsum += (e0 + e1) + (e2 + e3);
    uint2 w0, w1;
    w0.x = pkbf2(e0, e1); w0.y = pkbf2(e2, e3);
    w1.x = 0u; w1.y = 0u;
    *(uint2*)&Pw[lr * 40 + lq * 4]      = w0;
    *(uint2*)&Pw[lr * 40 + 16 + lq * 4] = w1;
    const bf16x8 pf  = *(const bf16x8*)&Pw[lr * 40 + lq * 8];
    const bf16x8 vf0 = *(const bf16x8*)&Vb[lr * VTP + m0 + lq * 8];
    const bf16x8 vf1 = *(const bf16x8*)&Vb[(16 + lr) * VTP + m0 + lq * 8];
    acc0 = __builtin_amdgcn_mfma_f32_16x16x32_bf16(pf, vf0, acc0, 0, 0, 0);
    acc1 = __builtin_amdgcn_mfma_f32_16x16x32_bf16(pf, vf1, acc1, 0, 0, 0);
  }

  // per-row denominator: sum over the 4 lq groups (lanes share row n=lr)
  lsum += __shfl_xor(lsum, 16);
  lsum += __shfl_xor(lsum, 32);

#pragma unroll
  for (int r = 0; r < 4; ++r) {
    const int row = lq * 4 + r;
    Ow[wv][row][lr]      = acc0[r];
    Ow[wv][row][16 + lr] = acc1[r];
  }
  if (lane < 16) Lw[wv][lane] = lsum;
  __syncthreads();
#pragma unroll
  for (int rep = 0; rep < 2; ++rep) {
    const int idx = rep * 256 + t;
    const int i = idx >> 5, d = idx & 31;
    const float num = Ow[0][i][d] + Ow[1][i][d] + Ow[2][i][d] + Ow[3][i][d];
    const float den = Lw[0][i] + Lw[1][i] + Lw[2][i] + Lw[3][i];
    const int n = n0 + i;
    if (n < NSEQ)
      AO[((size_t)(bh >> 3) * NSEQ + n) * CH + (bh & 7) * HD + d] = (u16)f2bf(num / den);
  }
}

// ---------------- kernel 4: output projection (A already bf16) ----------------
__global__ __launch_bounds__(256) void proj_o_kernel(
    const u16* __restrict__ AO, const float* __restrict__ Wo,
    const float* __restrict__ bo, float* __restrict__ out) {
  __shared__ u16 As[64][40], Bs[64][40];
  const int t = threadIdx.x;
  const int r0 = blockIdx.x * 64, c0 = blockIdx.y * 64;
  const int lane = t & 63, wv = t >> 6;
  const int wr = (wv >> 1) * 32, wc = (wv & 1) * 32;
  const int lr = lane & 15, lq = lane >> 4;
  const int arow = t >> 2, akq = (t & 3) * 8;
  const u16* Ar = AO + (size_t)(r0 + arow) * CH + akq;
  const float* Wr = Wo + (c0 + arow) * CH + akq;

  f32x4 acc[2][2];
#pragma unroll
  for (int i = 0; i < 2; ++i)
#pragma unroll
    for (int j = 0; j < 2; ++j) acc[i][j] = (f32x4){0.f, 0.f, 0.f, 0.f};

  for (int kc = 0; kc < CH; kc += 32) {
    const uint4 ap = *(const uint4*)(Ar + kc);
    const float4 b0 = *(const float4*)(Wr + kc);
    const float4 b1 = *(const float4*)(Wr + kc + 4);
    __syncthreads();
    *(uint4*)&As[arow][akq] = ap;
    *(uint4*)&Bs[arow][akq] = pack8(b0, b1);
    __syncthreads();
    const bf16x8 af0 = *(const bf16x8*)&As[wr + lr][lq * 8];
    const bf16x8 af1 = *(const bf16x8*)&As[wr + 16 + lr][lq * 8];
    const bf16x8 bf0 = *(const bf16x8*)&Bs[wc + lr][lq * 8];
    const bf16x8 bf1 = *(const bf16x8*)&Bs[wc + 16 + lr][lq * 8];
    acc[0][0] = __builtin_amdgcn_mfma_f32_16x16x32_bf16(af0, bf0, acc[0][0], 0, 0, 0);
    acc[0][1] = __builtin_amdgcn_mfma_f32_16x16x32_bf16(af0, bf1, acc[0][1], 0, 0, 0);
    acc[1][0] = __builtin_amdgcn_mfma_f32_16x16x32_bf16(af1, bf0, acc[1][0], 0, 0, 0);
    acc[1][1] = __builtin_amdgcn_mfma_f32_16x16x32_bf16(af1, bf1, acc[1][1], 0, 0, 0);
  }
#pragma unroll
  for (int tr = 0; tr < 2; ++tr)
#pragma unroll
    for (int tc = 0; tc < 2; ++tc) {
      const int col = c0 + wc + tc * 16 + lr;
      const float bi = bo[col];
#pragma unroll
      for (int r = 0; r < 4; ++r) {
        const int row = r0 + wr + tr * 16 + lq * 4 + r;
        out[(size_t)row * CH + col] = acc[tr][tc][r] + bi;
      }
    }
}

extern "C" void kernel_launch(void* const* d_in, const int* in_sizes, int n_in,
                              void* d_out, int out_size, void* d_ws, size_t ws_size,
                              hipStream_t stream) {
  (void)in_sizes; (void)n_in; (void)out_size; (void)ws_size;
  const float* query = (const float*)d_in[0];
  const float* key_  = (const float*)d_in[1];
  const float* value = (const float*)d_in[2];
  const float* prior = (const float*)d_in[3];
  const float* Wq = (const float*)d_in[4];
  const float* bq = (const float*)d_in[5];
  const float* Wk = (const float*)d_in[6];
  const float* bk = (const float*)d_in[7];
  const float* Wv = (const float*)d_in[8];
  const float* bv = (const float*)d_in[9];
  const float* Wo = (const float*)d_in[10];
  const float* bo = (const float*)d_in[11];

  u16* wsu = (u16*)d_ws;
  const size_t SZ = (size_t)16 * NH * NSEQ * HD;     // 3,686,400
  const size_t SZT = (size_t)16 * NH * HD * VTP;     // 3,735,552
  u16* Q  = wsu;
  u16* K  = wsu + SZ;
  u16* V  = wsu + 2 * SZ;
  u16* Vt = wsu + 3 * SZ;
  u16* AO = Vt + SZT + 64;                           // +64 pad for Vt tail over-read

  proj_qkv_kernel<<<dim3(225, 4, 3), 256, 0, stream>>>(
      query, key_, value, Wq, Wk, Wv, bq, bk, bv, Q, K, V);
  transpose_v_kernel<<<dim3(8, 128), 256, 0, stream>>>(V, Vt);
  attn_kernel<<<dim3(57, 128), 256, 0, stream>>>(Q, K, Vt, prior, AO);
  proj_o_kernel<<<dim3(225, 4), 256, 0, stream>>>(AO, Wo, bo, (float*)d_out);
}

// Round 4
// 674.623 us; speedup vs baseline: 1.0223x; 1.0015x over previous
//
#include <hip/hip_runtime.h>
#include <hip/hip_bf16.h>
#include <stdint.h>

#define NSEQ 900
#define CH 256
#define NH 8
#define HD 32
#define SCALE 0.17677669529663687f  // 32^-0.5
#define VTP 912                     // padded Vt row length (16B-aligned rows)

typedef unsigned short u16;
typedef __attribute__((ext_vector_type(8))) short bf16x8;
typedef __attribute__((ext_vector_type(4))) float f32x4;

__device__ __forceinline__ uint32_t f2bf(float f) {  // fp32 -> bf16 bits, RNE
  uint32_t u = __float_as_uint(f);
  return (u + 0x7fffu + ((u >> 16) & 1u)) >> 16;
}

__device__ __forceinline__ uint32_t pkbf2(float a, float b) {  // v_cvt_pk_bf16_f32
  __hip_bfloat162 h = __float22bfloat162_rn(make_float2(a, b));
  uint32_t u;
  __builtin_memcpy(&u, &h, 4);
  return u;
}

__device__ __forceinline__ uint4 pack8(float4 a, float4 b) {
  uint4 r;
  r.x = f2bf(a.x) | (f2bf(a.y) << 16);
  r.y = f2bf(a.z) | (f2bf(a.w) << 16);
  r.z = f2bf(b.x) | (f2bf(b.y) << 16);
  r.w = f2bf(b.z) | (f2bf(b.w) << 16);
  return r;
}

// Bijective XCD-chunked swizzle (m204): hardware block i lands on XCD i%8;
// remap so each XCD owns a CONTIGUOUS range of logical ids -> logical-adjacent
// blocks share L2. Valid for any nwg (handles nwg%8 != 0 bijectively).
__device__ __forceinline__ int xcd_chunk(int bid, int nwg) {
  const int q = nwg >> 3, r = nwg & 7;
  const int xcd = bid & 7, k = bid >> 3;
  return (xcd < r) ? (xcd * (q + 1) + k) : (r * (q + 1) + (xcd - r) * q + k);
}

// ---------------- kernel 1: QKV projections (bf16 MFMA, 64x64 tile) ----------
// out = X @ W^T + bias; X [14400][256] fp32 (row = n*16+b), W [256][256] fp32.
// Grid: flat 2700 = 675 row-tiles x 4 col-tiles; XCD-chunked + col-tiles of a
// row-tile logical-consecutive so the shared X tile is L2-hit 3 of 4 times.
// Epilogue: LDS-staged tile, 256B-coalesced uint4 stores into bf16 [B,H,N,D].
__global__ __launch_bounds__(256) void proj_qkv_kernel(
    const float* __restrict__ xq, const float* __restrict__ xk, const float* __restrict__ xv,
    const float* __restrict__ Wq, const float* __restrict__ Wk, const float* __restrict__ Wv,
    const float* __restrict__ bq, const float* __restrict__ bk, const float* __restrict__ bv,
    u16* __restrict__ Q, u16* __restrict__ K, u16* __restrict__ V) {
  __shared__ u16 smem[5120];  // K-loop: As(2560)+Bs(2560); epilogue: 64x72 tile
  const int t = threadIdx.x;
  const int lid = xcd_chunk(blockIdx.x, 2700);
  const int c0 = (lid & 3) * 64;
  const int rt = lid >> 2;            // 0..674
  const int mode = rt / 225;
  const int r0 = (rt % 225) * 64;
  const float* X    = (mode == 0) ? xq : (mode == 1) ? xk : xv;
  const float* W    = (mode == 0) ? Wq : (mode == 1) ? Wk : Wv;
  const float* bias = (mode == 0) ? bq : (mode == 1) ? bk : bv;
  u16* OUT          = (mode == 0) ? Q  : (mode == 1) ? K  : V;

  const int lane = t & 63, wv = t >> 6;
  const int wr = (wv >> 1) * 32, wc = (wv & 1) * 32;
  const int lr = lane & 15, lq = lane >> 4;
  const int arow = t >> 2, akq = (t & 3) * 8;
  const float* Xr = X + (r0 + arow) * CH + akq;
  const float* Wr = W + (c0 + arow) * CH + akq;

  f32x4 acc[2][2];
#pragma unroll
  for (int i = 0; i < 2; ++i)
#pragma unroll
    for (int j = 0; j < 2; ++j) acc[i][j] = (f32x4){0.f, 0.f, 0.f, 0.f};

  for (int kc = 0; kc < CH; kc += 32) {
    const float4 a0 = *(const float4*)(Xr + kc);
    const float4 a1 = *(const float4*)(Xr + kc + 4);
    const float4 b0 = *(const float4*)(Wr + kc);
    const float4 b1 = *(const float4*)(Wr + kc + 4);
    __syncthreads();
    *(uint4*)&smem[arow * 40 + akq]        = pack8(a0, a1);
    *(uint4*)&smem[2560 + arow * 40 + akq] = pack8(b0, b1);
    __syncthreads();
    const bf16x8 af0 = *(const bf16x8*)&smem[(wr + lr) * 40 + lq * 8];
    const bf16x8 af1 = *(const bf16x8*)&smem[(wr + 16 + lr) * 40 + lq * 8];
    const bf16x8 bf0 = *(const bf16x8*)&smem[2560 + (wc + lr) * 40 + lq * 8];
    const bf16x8 bf1 = *(const bf16x8*)&smem[2560 + (wc + 16 + lr) * 40 + lq * 8];
    acc[0][0] = __builtin_amdgcn_mfma_f32_16x16x32_bf16(af0, bf0, acc[0][0], 0, 0, 0);
    acc[0][1] = __builtin_amdgcn_mfma_f32_16x16x32_bf16(af0, bf1, acc[0][1], 0, 0, 0);
    acc[1][0] = __builtin_amdgcn_mfma_f32_16x16x32_bf16(af1, bf0, acc[1][0], 0, 0, 0);
    acc[1][1] = __builtin_amdgcn_mfma_f32_16x16x32_bf16(af1, bf1, acc[1][1], 0, 0, 0);
  }

  // stage tile into LDS (stride 72 u16), C layout: row=(lane>>4)*4+r, col=lane&15
  __syncthreads();
  const float qs = (mode == 0) ? SCALE : 1.0f;
#pragma unroll
  for (int tr = 0; tr < 2; ++tr)
#pragma unroll
    for (int tc = 0; tc < 2; ++tc) {
      const int col = wc + tc * 16 + lr;
      const float bi = bias[c0 + col];
#pragma unroll
      for (int r = 0; r < 4; ++r) {
        const int row = wr + tr * 16 + lq * 4 + r;
        smem[row * 72 + col] = (u16)f2bf((acc[tr][tc][r] + bi) * qs);
      }
    }
  __syncthreads();

  // coalesced store: task = ((b*2+h_l)*4 + nl)*4 + d16 -> 256B contiguous per 16 lanes
  const int n_base = r0 >> 4, h_base = c0 >> 5;
#pragma unroll
  for (int rep = 0; rep < 2; ++rep) {
    const int task = rep * 256 + t;
    const int d16 = task & 3, nl = (task >> 2) & 3, bhl = task >> 4;
    const int hl = bhl & 1, bb = bhl >> 1;
    const int lrow = nl * 16 + bb, lcol = hl * 32 + d16 * 8;
    const uint4 val = *(const uint4*)&smem[lrow * 72 + lcol];
    const size_t o = ((size_t)(bb * NH + h_base + hl) * NSEQ + n_base + nl) * HD + d16 * 8;
    *(uint4*)&OUT[o] = val;
  }
}

// ---------------- kernel 2: V [B,H,N,D] -> Vt [B,H,D,VTP] ----------------
__global__ __launch_bounds__(256) void transpose_v_kernel(
    const u16* __restrict__ V, u16* __restrict__ Vt) {
  __shared__ u16 T[32][136];
  const int t = threadIdx.x;
  const int bh = blockIdx.y;
  const int n0 = blockIdx.x * 128;
  {
    const int i = t >> 1, dh = (t & 1) * 16;
    const int n = min(n0 + i, NSEQ - 1);
    const uint4 v0 = *(const uint4*)&V[((size_t)bh * NSEQ + n) * HD + dh];
    const uint4 v1 = *(const uint4*)&V[((size_t)bh * NSEQ + n) * HD + dh + 8];
    const u16* u = (const u16*)&v0;
#pragma unroll
    for (int j = 0; j < 8; ++j) T[dh + j][i] = u[j];
    const u16* u2 = (const u16*)&v1;
#pragma unroll
    for (int j = 0; j < 8; ++j) T[dh + 8 + j][i] = u2[j];
  }
  __syncthreads();
  const int d = t >> 3, nb = (t & 7) * 16;
  u16* dst = Vt + ((size_t)bh * HD + d) * VTP + n0 + nb;
  if (n0 + nb + 15 < NSEQ) {
    *(uint4*)dst       = *(const uint4*)&T[d][nb];
    *(uint4*)(dst + 8) = *(const uint4*)&T[d][nb + 8];
  } else {
#pragma unroll
    for (int j = 0; j < 16; ++j) {
      const int col = n0 + nb + j;
      if (col < VTP) dst[j] = (col < NSEQ) ? T[d][nb + j] : (u16)0;  // zero pad cols
    }
  }
}

// ---------------- kernel 3: fused attention (MFMA, max-free softmax) --------
// Swapped QK^T: s = mfma(K,Q) puts S[n=n0+lr][m=m0+lq*4+r] in each lane ->
// per-lane FIXED n-row. prior becomes 2x float4 loads, P-pack 2x ds_write_b64,
// denominator a single per-lane accumulator. Ragged tail (cols 896..899) is
// handled outside the loop. Grid flat 7296; XCD-chunked so the 57 blocks
// sharing one bh's K/Vt are L2-colocated.
__global__ __launch_bounds__(256) void attn_kernel(
    const u16* __restrict__ Q, const u16* __restrict__ K,
    const u16* __restrict__ Vt, const float* __restrict__ prior,
    u16* __restrict__ AO) {
  __shared__ u16 Plds[4][640];       // per-wave 16x32 P tile, 40-u16 row stride
  __shared__ float Ow[4][16][32];
  __shared__ float Lw[4][16];

  const int t = threadIdx.x;
  const int lid = xcd_chunk(blockIdx.x, 57 * 128);
  const int bh = lid / 57;
  const int n0 = (lid % 57) * 16;
  const int lane = t & 63, wv = t >> 6;
  const int lr = lane & 15, lq = lane >> 4;

  const u16* Qb = Q + (size_t)bh * NSEQ * HD;
  const u16* Kb = K + (size_t)bh * NSEQ * HD;
  const u16* Vb = Vt + (size_t)bh * HD * VTP;
  const float* Pb = prior + (size_t)bh * NSEQ * NSEQ;

  const int qrow = min(n0 + lr, NSEQ - 1);
  const bf16x8 qf = *(const bf16x8*)&Qb[qrow * HD + lq * 8];
  const float* Prow = Pb + (size_t)qrow * NSEQ;  // this lane's prior row (n)

  f32x4 acc0 = {0.f, 0.f, 0.f, 0.f};
  f32x4 acc1 = {0.f, 0.f, 0.f, 0.f};
  float lsum = 0.f;
  u16* Pw = &Plds[wv][0];

  for (int c = wv; c < 28; c += 4) {  // 28 full chunks of 32 = cols 0..895
    const int m0 = c * 32;
    const bf16x8 kf0 = *(const bf16x8*)&Kb[(m0 + lr) * HD + lq * 8];
    const bf16x8 kf1 = *(const bf16x8*)&Kb[(m0 + 16 + lr) * HD + lq * 8];
    const float4 pA = *(const float4*)&Prow[m0 + lq * 4];
    const float4 pB = *(const float4*)&Prow[m0 + 16 + lq * 4];
    const f32x4 z = {0.f, 0.f, 0.f, 0.f};
    const f32x4 s0 = __builtin_amdgcn_mfma_f32_16x16x32_bf16(kf0, qf, z, 0, 0, 0);
    const f32x4 s1 = __builtin_amdgcn_mfma_f32_16x16x32_bf16(kf1, qf, z, 0, 0, 0);
    const float e0 = __expf(s0[0] * pA.x), e1 = __expf(s0[1] * pA.y);
    const float e2 = __expf(s0[2] * pA.z), e3 = __expf(s0[3] * pA.w);
    const float e4 = __expf(s1[0] * pB.x), e5 = __expf(s1[1] * pB.y);
    const float e6 = __expf(s1[2] * pB.z), e7 = __expf(s1[3] * pB.w);
    lsum += ((e0 + e1) + (e2 + e3)) + ((e4 + e5) + (e6 + e7));
    uint2 w0, w1;
    w0.x = pkbf2(e0, e1); w0.y = pkbf2(e2, e3);
    w1.x = pkbf2(e4, e5); w1.y = pkbf2(e6, e7);
    *(uint2*)&Pw[lr * 40 + lq * 4]      = w0;
    *(uint2*)&Pw[lr * 40 + 16 + lq * 4] = w1;
    const bf16x8 pf  = *(const bf16x8*)&Pw[lr * 40 + lq * 8];
    const bf16x8 vf0 = *(const bf16x8*)&Vb[lr * VTP + m0 + lq * 8];
    const bf16x8 vf1 = *(const bf16x8*)&Vb[(16 + lr) * VTP + m0 + lq * 8];
    acc0 = __builtin_amdgcn_mfma_f32_16x16x32_bf16(pf, vf0, acc0, 0, 0, 0);
    acc1 = __builtin_amdgcn_mfma_f32_16x16x32_bf16(pf, vf1, acc1, 0, 0, 0);
  }

  if (wv == 0) {  // tail chunk: cols 896..899 valid (4 of 32)
    const int m0 = 896;
    const bf16x8 kf0 = *(const bf16x8*)&Kb[min(m0 + lr, NSEQ - 1) * HD + lq * 8];
    const float4 pA = *(const float4*)&Prow[m0];  // cols 896..899
    const f32x4 z = {0.f, 0.f, 0.f, 0.f};
    const f32x4 s0 = __builtin_amdgcn_mfma_f32_16x16x32_bf16(kf0, qf, z, 0, 0, 0);
    float e0 = 0.f, e1 = 0.f, e2 = 0.f, e3 = 0.f;
    if (lq == 0) {  // only C-rows 0..3 (m=896..899) are valid
      e0 = __expf(s0[0] * pA.x); e1 = __expf(s0[1] * pA.y);
      e2 = __expf(s0[2] * pA.z); e3 = __expf(s0[3] * pA.w);
    }
    lsum += (e0 + e1) + (e2 + e3);
    uint2 w0, w1;
    w0.x = pkbf2(e0, e1); w0.y = pkbf2(e2, e3);
    w1.x = 0u; w1.y = 0u;
    *(uint2*)&Pw[lr * 40 + lq * 4]      = w0;
    *(uint2*)&Pw[lr * 40 + 16 + lq * 4] = w1;
    const bf16x8 pf  = *(const bf16x8*)&Pw[lr * 40 + lq * 8];
    const bf16x8 vf0 = *(const bf16x8*)&Vb[lr * VTP + m0 + lq * 8];
    const bf16x8 vf1 = *(const bf16x8*)&Vb[(16 + lr) * VTP + m0 + lq * 8];
    acc0 = __builtin_amdgcn_mfma_f32_16x16x32_bf16(pf, vf0, acc0, 0, 0, 0);
    acc1 = __builtin_amdgcn_mfma_f32_16x16x32_bf16(pf, vf1, acc1, 0, 0, 0);
  }

  // per-row denominator: sum over the 4 lq groups (lanes share row n=lr)
  lsum += __shfl_xor(lsum, 16);
  lsum += __shfl_xor(lsum, 32);

#pragma unroll
  for (int r = 0; r < 4; ++r) {
    const int row = lq * 4 + r;
    Ow[wv][row][lr]      = acc0[r];
    Ow[wv][row][16 + lr] = acc1[r];
  }
  if (lane < 16) Lw[wv][lane] = lsum;
  __syncthreads();
#pragma unroll
  for (int rep = 0; rep < 2; ++rep) {
    const int idx = rep * 256 + t;
    const int i = idx >> 5, d = idx & 31;
    const float num = Ow[0][i][d] + Ow[1][i][d] + Ow[2][i][d] + Ow[3][i][d];
    const float den = Lw[0][i] + Lw[1][i] + Lw[2][i] + Lw[3][i];
    const int n = n0 + i;
    if (n < NSEQ)
      AO[((size_t)(bh >> 3) * NSEQ + n) * CH + (bh & 7) * HD + d] = (u16)f2bf(num / den);
  }
}

// ---------------- kernel 4: output projection (A already bf16) ----------------
// Grid flat 900 = 225 row-tiles x 4 col-tiles, XCD-chunked like proj_qkv.
__global__ __launch_bounds__(256) void proj_o_kernel(
    const u16* __restrict__ AO, const float* __restrict__ Wo,
    const float* __restrict__ bo, float* __restrict__ out) {
  __shared__ u16 As[64][40], Bs[64][40];
  const int t = threadIdx.x;
  const int lid = xcd_chunk(blockIdx.x, 900);
  const int r0 = (lid >> 2) * 64, c0 = (lid & 3) * 64;
  const int lane = t & 63, wv = t >> 6;
  const int wr = (wv >> 1) * 32, wc = (wv & 1) * 32;
  const int lr = lane & 15, lq = lane >> 4;
  const int arow = t >> 2, akq = (t & 3) * 8;
  const u16* Ar = AO + (size_t)(r0 + arow) * CH + akq;
  const float* Wr = Wo + (c0 + arow) * CH + akq;

  f32x4 acc[2][2];
#pragma unroll
  for (int i = 0; i < 2; ++i)
#pragma unroll
    for (int j = 0; j < 2; ++j) acc[i][j] = (f32x4){0.f, 0.f, 0.f, 0.f};

  for (int kc = 0; kc < CH; kc += 32) {
    const uint4 ap = *(const uint4*)(Ar + kc);
    const float4 b0 = *(const float4*)(Wr + kc);
    const float4 b1 = *(const float4*)(Wr + kc + 4);
    __syncthreads();
    *(uint4*)&As[arow][akq] = ap;
    *(uint4*)&Bs[arow][akq] = pack8(b0, b1);
    __syncthreads();
    const bf16x8 af0 = *(const bf16x8*)&As[wr + lr][lq * 8];
    const bf16x8 af1 = *(const bf16x8*)&As[wr + 16 + lr][lq * 8];
    const bf16x8 bf0 = *(const bf16x8*)&Bs[wc + lr][lq * 8];
    const bf16x8 bf1 = *(const bf16x8*)&Bs[wc + 16 + lr][lq * 8];
    acc[0][0] = __builtin_amdgcn_mfma_f32_16x16x32_bf16(af0, bf0, acc[0][0], 0, 0, 0);
    acc[0][1] = __builtin_amdgcn_mfma_f32_16x16x32_bf16(af0, bf1, acc[0][1], 0, 0, 0);
    acc[1][0] = __builtin_amdgcn_mfma_f32_16x16x32_bf16(af1, bf0, acc[1][0], 0, 0, 0);
    acc[1][1] = __builtin_amdgcn_mfma_f32_16x16x32_bf16(af1, bf1, acc[1][1], 0, 0, 0);
  }
#pragma unroll
  for (int tr = 0; tr < 2; ++tr)
#pragma unroll
    for (int tc = 0; tc < 2; ++tc) {
      const int col = c0 + wc + tc * 16 + lr;
      const float bi = bo[col];
#pragma unroll
      for (int r = 0; r < 4; ++r) {
        const int row = r0 + wr + tr * 16 + lq * 4 + r;
        out[(size_t)row * CH + col] = acc[tr][tc][r] + bi;
      }
    }
}

extern "C" void kernel_launch(void* const* d_in, const int* in_sizes, int n_in,
                              void* d_out, int out_size, void* d_ws, size_t ws_size,
                              hipStream_t stream) {
  (void)in_sizes; (void)n_in; (void)out_size; (void)ws_size;
  const float* query = (const float*)d_in[0];
  const float* key_  = (const float*)d_in[1];
  const float* value = (const float*)d_in[2];
  const float* prior = (const float*)d_in[3];
  const float* Wq = (const float*)d_in[4];
  const float* bq = (const float*)d_in[5];
  const float* Wk = (const float*)d_in[6];
  const float* bk = (const float*)d_in[7];
  const float* Wv = (const float*)d_in[8];
  const float* bv = (const float*)d_in[9];
  const float* Wo = (const float*)d_in[10];
  const float* bo = (const float*)d_in[11];

  u16* wsu = (u16*)d_ws;
  const size_t SZ = (size_t)16 * NH * NSEQ * HD;     // 3,686,400
  const size_t SZT = (size_t)16 * NH * HD * VTP;     // 3,735,552
  u16* Q  = wsu;
  u16* K  = wsu + SZ;
  u16* V  = wsu + 2 * SZ;
  u16* Vt = wsu + 3 * SZ;
  u16* AO = Vt + SZT + 64;                           // +64 pad for Vt tail over-read

  proj_qkv_kernel<<<dim3(2700), 256, 0, stream>>>(
      query, key_, value, Wq, Wk, Wv, bq, bk, bv, Q, K, V);
  transpose_v_kernel<<<dim3(8, 128), 256, 0, stream>>>(V, Vt);
  attn_kernel<<<dim3(57 * 128), 256, 0, stream>>>(Q, K, Vt, prior, AO);
  proj_o_kernel<<<dim3(900), 256, 0, stream>>>(AO, Wo, bo, (float*)d_out);
}